// Round 15
// baseline (259.400 us; speedup 1.0000x reference)
//
#include <hip/hip_runtime.h>
#include <hip/hip_fp16.h>

#define NNODES 50000
#define EORIG  1600000
#define ETOT   (EORIG + NNODES)
#define NEG 0.2f
#define BSH 7
#define NBUCK ((NNODES + 127) >> BSH)   // 391
#define BCAP 5120
#define NRT (NNODES / 16)               // 3125
#define EPB 4096
#define NBE ((ETOT + EPB - 1) / EPB)    // 403
#define LOG2E 1.44269504f

typedef _Float16 v2h __attribute__((ext_vector_type(2)));
typedef _Float16 v8h __attribute__((ext_vector_type(8)));
typedef float    v4f __attribute__((ext_vector_type(4)));

__device__ __forceinline__ float hdot2v(v2h a, v2h b, float c) {
#if __has_builtin(__builtin_amdgcn_fdot2)
    return __builtin_amdgcn_fdot2(a, b, c, false);
#else
    return c + (float)a.x * (float)b.x + (float)a.y * (float)b.y;
#endif
}

__device__ __forceinline__ float fexp2(float t) {
#if __has_builtin(__builtin_amdgcn_exp2f)
    return __builtin_amdgcn_exp2f(t);
#else
    return exp2f(t);
#endif
}

// ---------------------------------------------------------------------------
// Merged prep: blocks [0,NBE) partition edges; blocks [NBE,NBE+192) pack W.
// ---------------------------------------------------------------------------
__global__ __launch_bounds__(256) void prep_kernel(
    const int* __restrict__ src, const int* __restrict__ dst,
    int* __restrict__ bcur, unsigned int* __restrict__ pairs,
    const float* __restrict__ Wl, const float* __restrict__ Wr,
    const float* __restrict__ Wlmu, const float* __restrict__ Wllv,
    const float* __restrict__ Wrmu, const float* __restrict__ Wrlv,
    __half* __restrict__ WT, __half* __restrict__ WT2)
{
    if (blockIdx.x >= NBE) {
        int id = (blockIdx.x - NBE) * 256 + threadIdx.x;
        if (id < 32768) {
            int k = id >> 8, c = id & 255;
            float v = (c < 128) ? Wl[k * 128 + c] : Wr[k * 128 + (c - 128)];
            WT[c * 128 + k] = __float2half(v);
        } else if (id < 49152) {
            int loc = id - 32768;
            int k = loc >> 7, c = loc & 127;
            int sel = c >> 5, cc = c & 31;
            const float* W = sel == 0 ? Wlmu : sel == 1 ? Wllv : sel == 2 ? Wrmu : Wrlv;
            WT2[c * 128 + k] = __float2half(W[k * 32 + cc]);
        }
        return;
    }

    __shared__ int cnt[NBUCK];
    __shared__ int gbase[NBUCK];
    const int e0 = blockIdx.x * EPB;

    for (int i = threadIdx.x; i < NBUCK; i += 256) cnt[i] = 0;
    __syncthreads();

    for (int i = threadIdx.x; i < EPB; i += 256) {
        int e = e0 + i;
        if (e >= ETOT) break;
        int d = (e < EORIG) ? dst[e] : e - EORIG;
        atomicAdd(&cnt[d >> BSH], 1);
    }
    __syncthreads();

    for (int b = threadIdx.x; b < NBUCK; b += 256) {
        int c = cnt[b];
        gbase[b] = c ? (b * BCAP + atomicAdd(&bcur[b], c)) : 0;
        cnt[b] = 0;
    }
    __syncthreads();

    for (int i = threadIdx.x; i < EPB; i += 256) {
        int e = e0 + i;
        if (e >= ETOT) break;
        int s, d;
        if (e < EORIG) { s = src[e]; d = dst[e]; }
        else           { s = d = e - EORIG; }
        int b = d >> BSH;
        int slot = atomicAdd(&cnt[b], 1);
        pairs[gbase[b] + slot] = (unsigned)s | ((unsigned)(d & 127) << 16);
    }
}

// ---------------------------------------------------------------------------
// csrfill: per-bucket local hist+scan -> begend int2 + ushort csr.
// ---------------------------------------------------------------------------
__global__ __launch_bounds__(256) void csrfill_kernel(
    const unsigned int* __restrict__ pairs, const int* __restrict__ bcur,
    int2* __restrict__ begend, unsigned short* __restrict__ csr)
{
    __shared__ int cnt[128];
    __shared__ int lofs[128];
    __shared__ int scnt[128];
    const int b = blockIdx.x, n0 = b << BSH;
    const int nn = min(128, NNODES - n0);
    const int pbase = b * BCAP;
    const int pend = pbase + bcur[b];
    const int t = threadIdx.x;

    if (t < 128) { cnt[t] = 0; scnt[t] = 0; }
    __syncthreads();
    for (int i = pbase + t; i < pend; i += 256)
        atomicAdd(&cnt[pairs[i] >> 16], 1);
    __syncthreads();

    int myc = (t < 128) ? cnt[t] : 0;
    if (t < 128) lofs[t] = myc;
    __syncthreads();
    for (int off = 1; off < 128; off <<= 1) {
        int v = (t < 128 && t >= off) ? lofs[t - off] : 0;
        __syncthreads();
        if (t < 128) lofs[t] += v;
        __syncthreads();
    }
    if (t < 128) lofs[t] = pbase + lofs[t] - myc;
    __syncthreads();

    if (t < nn) begend[n0 + t] = make_int2(lofs[t], lofs[t] + myc);

    for (int i = pbase + t; i < pend; i += 256) {
        unsigned pr = pairs[i];
        int l = pr >> 16;
        int slot = atomicAdd(&scnt[l], 1);
        csr[lofs[l] + slot] = (unsigned short)(pr & 0xFFFFu);
    }
}

// ---------------------------------------------------------------------------
// Layer-1 dual linear via MFMA; outputs HEAD-SLICED:
//   xlh[h][n][32], xrh[h][n][32]  (h = output col / 32)
// ---------------------------------------------------------------------------
__global__ __launch_bounds__(256) void lin1_kernel(
    const float* __restrict__ x, const __half* __restrict__ WT,
    const float* __restrict__ bl, const float* __restrict__ br,
    __half* __restrict__ xlh, __half* __restrict__ xrh)
{
    int rt = (blockIdx.x * 256 + threadIdx.x) >> 6;
    if (rt >= NRT) return;
    int l  = threadIdx.x & 63;
    int lr = l & 15, lg = l >> 4;
    int row = rt * 16 + lr;

    v8h a[4];
    const float4* xrow = reinterpret_cast<const float4*>(x + (size_t)row * 128);
    #pragma unroll
    for (int ks = 0; ks < 4; ++ks) {
        float4 f0 = xrow[ks * 8 + lg * 2];
        float4 f1 = xrow[ks * 8 + lg * 2 + 1];
        v8h t;
        t[0]=(_Float16)f0.x; t[1]=(_Float16)f0.y; t[2]=(_Float16)f0.z; t[3]=(_Float16)f0.w;
        t[4]=(_Float16)f1.x; t[5]=(_Float16)f1.y; t[6]=(_Float16)f1.z; t[7]=(_Float16)f1.w;
        a[ks] = t;
    }

    const uint4* wt4 = reinterpret_cast<const uint4*>(WT);
    #pragma unroll 4
    for (int ct = 0; ct < 16; ++ct) {
        int c = ct * 16 + lr;
        v4f acc = {0.f, 0.f, 0.f, 0.f};
        #pragma unroll
        for (int ks = 0; ks < 4; ++ks) {
            union { uint4 u; v8h h; } B;
            B.u = wt4[(size_t)c * 16 + ks * 4 + lg];
            acc = __builtin_amdgcn_mfma_f32_16x16x32_f16(a[ks], B.h, acc, 0, 0, 0);
        }
        float bb = (c < 128) ? bl[c] : br[c - 128];
        int c2 = (c < 128) ? c : c - 128;
        __half* dstp = (c < 128) ? xlh : xrh;
        int hh = c2 >> 5, cc = c2 & 31;
        #pragma unroll
        for (int j = 0; j < 4; ++j) {
            int orow = rt * 16 + lg * 4 + j;
            dstp[((size_t)hh * NNODES + orow) * 32 + cc] = __float2half(acc[j] + bb);
        }
    }
}

// ---------------------------------------------------------------------------
// Layer-2 quad linear via MFMA. A read from head-sliced h16h (head = ks).
// Outputs sliced: xi[h][n][32] (h=0 mu,1 lv), xr2[h][n][32].
// ---------------------------------------------------------------------------
__global__ __launch_bounds__(256) void lin2_kernel(
    const __half* __restrict__ h16h, const __half* __restrict__ WT2,
    const float* __restrict__ blmu, const float* __restrict__ bllv,
    const float* __restrict__ brmu, const float* __restrict__ brlv,
    __half* __restrict__ xi, __half* __restrict__ xr2)
{
    int rt = (blockIdx.x * 256 + threadIdx.x) >> 6;
    if (rt >= NRT) return;
    int l  = threadIdx.x & 63;
    int lr = l & 15, lg = l >> 4;
    int row = rt * 16 + lr;

    v8h a[4];
    #pragma unroll
    for (int ks = 0; ks < 4; ++ks) {
        union { uint4 u; v8h h; } A;
        A.u = *reinterpret_cast<const uint4*>(
            h16h + ((size_t)ks * NNODES + row) * 32 + lg * 8);
        a[ks] = A.h;
    }

    const uint4* wt4 = reinterpret_cast<const uint4*>(WT2);
    #pragma unroll 4
    for (int ct = 0; ct < 8; ++ct) {
        int c = ct * 16 + lr;
        v4f acc = {0.f, 0.f, 0.f, 0.f};
        #pragma unroll
        for (int ks = 0; ks < 4; ++ks) {
            union { uint4 u; v8h h; } B;
            B.u = wt4[(size_t)c * 16 + ks * 4 + lg];
            acc = __builtin_amdgcn_mfma_f32_16x16x32_f16(a[ks], B.h, acc, 0, 0, 0);
        }
        int sel = c >> 5, cc = c & 31;
        const float* bp = sel == 0 ? blmu : sel == 1 ? bllv : sel == 2 ? brmu : brlv;
        float bb = bp[cc];
        __half* dstp = (sel < 2) ? (xi + (size_t)sel * NNODES * 32)
                                 : (xr2 + (size_t)(sel - 2) * NNODES * 32);
        #pragma unroll
        for (int j = 0; j < 4; ++j) {
            int orow = rt * 16 + lg * 4 + j;
            dstp[(size_t)orow * 32 + cc] = __float2half(acc[j] + bb);
        }
    }
}

// ---------------------------------------------------------------------------
// Layer-1 gather, HEAD-SLICED + XCD-partitioned.
// block = slot s (=blockIdx%8); head = s>>1; 4 waves = 4 nodes.
// wave lane = g*8 + c: g = edge slot (8/iter), c = 4-ch chunk (8B).
// Per-XCD working set = one 3.2MB head slice -> L2-resident.
// ---------------------------------------------------------------------------
__global__ __launch_bounds__(256) void gat_gather1(
    const __half* __restrict__ xlh, const __half* __restrict__ xrh,
    const float* __restrict__ att, const float* __restrict__ bias,
    const int2* __restrict__ begend, const unsigned short* __restrict__ csr,
    __half* __restrict__ h16h)
{
    int b = blockIdx.x;
    int s = b & 7;
    int head = s >> 1;
    int d = (b >> 3) * 8 + (s & 1) * 4 + (threadIdx.x >> 6);
    if (d >= NNODES) return;
    int lane = threadIdx.x & 63;
    int g = lane >> 3;
    int c = lane & 7;

    v2h xrv[2], atv[2];
    {
        union { uint2 u; v2h v[2]; } R;
        R.u = reinterpret_cast<const uint2*>(xrh + ((size_t)head * NNODES + d) * 32)[c];
        xrv[0] = R.v[0]; xrv[1] = R.v[1];
        float4 a = reinterpret_cast<const float4*>(att + head * 32)[c];
        atv[0] = (v2h){(_Float16)(a.x*LOG2E), (_Float16)(a.y*LOG2E)};
        atv[1] = (v2h){(_Float16)(a.z*LOG2E), (_Float16)(a.w*LOG2E)};
    }
    const v2h neg2 = (v2h){(_Float16)NEG, (_Float16)NEG};

    int2 be = begend[d];
    int beg = be.x, end = be.y;          // deg >= 1 (self-loop)
    int nI = (end - beg + 7) >> 3;
    const uint2* xlu = reinterpret_cast<const uint2*>(xlh + (size_t)head * NNODES * 32);

    float den = 0.f;
    float acc[4] = {0.f, 0.f, 0.f, 0.f};

    auto compute = [&](uint2 U, bool val) {
        union { uint2 u; v2h v[2]; } X; X.u = U;
        v2h s0 = X.v[0] + xrv[0];
        v2h s1 = X.v[1] + xrv[1];
        v2h l0 = __builtin_elementwise_max(s0, s0 * neg2);
        v2h l1 = __builtin_elementwise_max(s1, s1 * neg2);
        float t = hdot2v(l0, atv[0], 0.f);
        t = hdot2v(l1, atv[1], t);
        t += __shfl_xor(t, 1, 64);
        t += __shfl_xor(t, 2, 64);
        t += __shfl_xor(t, 4, 64);
        float p = val ? fexp2(t) : 0.f;
        den += p;
        acc[0] += p * (float)X.v[0].x;
        acc[1] += p * (float)X.v[0].y;
        acc[2] += p * (float)X.v[1].x;
        acc[3] += p * (float)X.v[1].y;
    };

    // depth-2 pipeline
    int sA = beg + g;
    bool vA = sA < end;
    int iA = csr[vA ? sA : end - 1];
    uint2 rA = xlu[(size_t)iA * 8 + c];
    int sB = beg + 8 + g;
    bool vB = sB < end;
    int iB = csr[vB ? sB : end - 1];

    for (int it = 0; it < nI; ++it) {
        int sC = beg + (it + 2) * 8 + g;
        bool vC = sC < end;
        int iC = csr[vC ? sC : end - 1];
        uint2 rB = xlu[(size_t)iB * 8 + c];
        compute(rA, vA);
        rA = rB; vA = vB; iB = iC; vB = vC;
    }

    den += __shfl_xor(den, 8, 64);
    den += __shfl_xor(den, 16, 64);
    den += __shfl_xor(den, 32, 64);
    #pragma unroll
    for (int j = 0; j < 4; ++j) {
        acc[j] += __shfl_xor(acc[j], 8, 64);
        acc[j] += __shfl_xor(acc[j], 16, 64);
        acc[j] += __shfl_xor(acc[j], 32, 64);
    }

    if (g == 0) {
        float r = 1.f / den;
        float4 bb = reinterpret_cast<const float4*>(bias + head * 32)[c];
        __half hv[4];
        hv[0] = __float2half(fmaxf(acc[0] * r + bb.x, 0.f));
        hv[1] = __float2half(fmaxf(acc[1] * r + bb.y, 0.f));
        hv[2] = __float2half(fmaxf(acc[2] * r + bb.z, 0.f));
        hv[3] = __float2half(fmaxf(acc[3] * r + bb.w, 0.f));
        *reinterpret_cast<uint2*>(&h16h[((size_t)head * NNODES + d) * 32 + c * 4]) =
            *reinterpret_cast<uint2*>(hv);
    }
}

// ---------------------------------------------------------------------------
// Layer-2 gather, sliced mu/lv + XCD-partitioned.
// block slot s: head = s>>2 (0 mu, 1 lv); nodes (b>>3)*16 + (s&3)*4 + wave.
// ---------------------------------------------------------------------------
__global__ __launch_bounds__(256) void gat_gather2(
    const __half* __restrict__ xi, const __half* __restrict__ xr2,
    const float* __restrict__ atmu, const float* __restrict__ atlv,
    const float* __restrict__ bmu,  const float* __restrict__ blv,
    const int2* __restrict__ begend, const unsigned short* __restrict__ csr,
    float* __restrict__ out)
{
    int b = blockIdx.x;
    int s = b & 7;
    int head = s >> 2;                    // 0 mu, 1 lv
    int d = (b >> 3) * 16 + (s & 3) * 4 + (threadIdx.x >> 6);
    if (d >= NNODES) return;
    int lane = threadIdx.x & 63;
    int g = lane >> 3;
    int c = lane & 7;

    const __half* xip  = xi  + (size_t)head * NNODES * 32;
    const __half* xrp  = xr2 + (size_t)head * NNODES * 32;
    const float*  atp  = head ? atlv : atmu;
    const float*  bp   = head ? blv : bmu;

    v2h xrv[2], atv[2];
    {
        union { uint2 u; v2h v[2]; } R;
        R.u = reinterpret_cast<const uint2*>(xrp + (size_t)d * 32)[c];
        xrv[0] = R.v[0]; xrv[1] = R.v[1];
        float4 a = reinterpret_cast<const float4*>(atp)[c];
        atv[0] = (v2h){(_Float16)(a.x*LOG2E), (_Float16)(a.y*LOG2E)};
        atv[1] = (v2h){(_Float16)(a.z*LOG2E), (_Float16)(a.w*LOG2E)};
    }
    const v2h neg2 = (v2h){(_Float16)NEG, (_Float16)NEG};

    int2 be = begend[d];
    int beg = be.x, end = be.y;
    int nI = (end - beg + 7) >> 3;
    const uint2* xiu = reinterpret_cast<const uint2*>(xip);

    float den = 0.f;
    float acc[4] = {0.f, 0.f, 0.f, 0.f};

    auto compute = [&](uint2 U, bool val) {
        union { uint2 u; v2h v[2]; } X; X.u = U;
        v2h s0 = X.v[0] + xrv[0];
        v2h s1 = X.v[1] + xrv[1];
        v2h l0 = __builtin_elementwise_max(s0, s0 * neg2);
        v2h l1 = __builtin_elementwise_max(s1, s1 * neg2);
        float t = hdot2v(l0, atv[0], 0.f);
        t = hdot2v(l1, atv[1], t);
        t += __shfl_xor(t, 1, 64);
        t += __shfl_xor(t, 2, 64);
        t += __shfl_xor(t, 4, 64);
        float p = val ? fexp2(t) : 0.f;
        den += p;
        acc[0] += p * (float)X.v[0].x;
        acc[1] += p * (float)X.v[0].y;
        acc[2] += p * (float)X.v[1].x;
        acc[3] += p * (float)X.v[1].y;
    };

    int sA = beg + g;
    bool vA = sA < end;
    int iA = csr[vA ? sA : end - 1];
    uint2 rA = xiu[(size_t)iA * 8 + c];
    int sB = beg + 8 + g;
    bool vB = sB < end;
    int iB = csr[vB ? sB : end - 1];

    for (int it = 0; it < nI; ++it) {
        int sC = beg + (it + 2) * 8 + g;
        bool vC = sC < end;
        int iC = csr[vC ? sC : end - 1];
        uint2 rB = xiu[(size_t)iB * 8 + c];
        compute(rA, vA);
        rA = rB; vA = vB; iB = iC; vB = vC;
    }

    den += __shfl_xor(den, 8, 64);
    den += __shfl_xor(den, 16, 64);
    den += __shfl_xor(den, 32, 64);
    #pragma unroll
    for (int j = 0; j < 4; ++j) {
        acc[j] += __shfl_xor(acc[j], 8, 64);
        acc[j] += __shfl_xor(acc[j], 16, 64);
        acc[j] += __shfl_xor(acc[j], 32, 64);
    }

    if (g == 0) {
        float r = 1.f / den;
        float4 bb = reinterpret_cast<const float4*>(bp)[c];
        float4 o = make_float4(acc[0]*r+bb.x, acc[1]*r+bb.y,
                               acc[2]*r+bb.z, acc[3]*r+bb.w);
        float* base_out = out + (head ? 1600000 : 0);
        reinterpret_cast<float4*>(base_out + (size_t)d * 32)[c] = o;
    }
}

extern "C" void kernel_launch(void* const* d_in, const int* in_sizes, int n_in,
                              void* d_out, int out_size, void* d_ws, size_t ws_size,
                              hipStream_t stream) {
    const float* x    = (const float*)d_in[0];
    const int*   ei   = (const int*)d_in[1];
    const float* Wl1  = (const float*)d_in[2];
    const float* bl1  = (const float*)d_in[3];
    const float* Wr1  = (const float*)d_in[4];
    const float* br1  = (const float*)d_in[5];
    const float* att1 = (const float*)d_in[6];
    const float* b1   = (const float*)d_in[7];
    const float* Wlmu = (const float*)d_in[8];
    const float* blmu = (const float*)d_in[9];
    const float* Wrmu = (const float*)d_in[10];
    const float* brmu = (const float*)d_in[11];
    const float* atmu = (const float*)d_in[12];
    const float* bmu  = (const float*)d_in[13];
    const float* Wllv = (const float*)d_in[14];
    const float* bllv = (const float*)d_in[15];
    const float* Wrlv = (const float*)d_in[16];
    const float* brlv = (const float*)d_in[17];
    const float* atlv = (const float*)d_in[18];
    const float* blv  = (const float*)d_in[19];

    float* out = (float*)d_out;
    float* ws  = (float*)d_ws;

    __half* xlh  = (__half*)ws;                      // 4 x [N][32] halves
    __half* xrh  = (__half*)(ws + 3200000);          // 4 x [N][32]
    __half* h16h = (__half*)(ws + 6400000);          // 4 x [N][32]
    __half* WT   = (__half*)(ws + 9600000);          // 32768 halves
    __half* WT2  = (__half*)(ws + 9620000);          // 16384 halves

    __half* xi  = (__half*)ws;                       // 2 x [N][32] (aliases xlh)
    __half* xr2 = (__half*)(ws + 1600000);           // 2 x [N][32]

    int* ip = (int*)(ws + 10000000);
    unsigned int*   pairs  = (unsigned int*)ip;               // 2,001,920
    int*            bcur   = ip + 2001920;                    // 392
    int2*           begend = (int2*)(ip + 2002312);           // 50,000 int2
    unsigned short* csr    = (unsigned short*)(ip + 2102312); // 2,001,920 u16

    const int* srcp = ei;
    const int* dstp = ei + EORIG;

    // ---- CSR build + weight pack ----
    hipMemsetAsync(bcur, 0, NBUCK * sizeof(int), stream);
    prep_kernel<<<NBE + 192, 256, 0, stream>>>(
        srcp, dstp, bcur, pairs, Wl1, Wr1, Wlmu, Wllv, Wrmu, Wrlv, WT, WT2);
    csrfill_kernel<<<NBUCK, 256, 0, stream>>>(pairs, bcur, begend, csr);

    // ---- layer 1 ----
    lin1_kernel<<<(NRT + 3) / 4, 256, 0, stream>>>(x, WT, bl1, br1, xlh, xrh);

    gat_gather1<<<(NNODES / 8) * 8, 256, 0, stream>>>(
        xlh, xrh, att1, b1, begend, csr, h16h);

    // ---- layer 2 ----
    lin2_kernel<<<(NRT + 3) / 4, 256, 0, stream>>>(
        h16h, WT2, blmu, bllv, brmu, brlv, xi, xr2);

    gat_gather2<<<(NNODES / 16) * 8, 256, 0, stream>>>(
        xi, xr2, atmu, atlv, bmu, blv, begend, csr, out);
}

// Round 16
// 199.710 us; speedup vs baseline: 1.2989x; 1.2989x over previous
//
#include <hip/hip_runtime.h>
#include <hip/hip_fp16.h>

#define NNODES 50000
#define EORIG  1600000
#define ETOT   (EORIG + NNODES)
#define NEG 0.2f
#define BSH 7
#define NBUCK ((NNODES + 127) >> BSH)   // 391
#define BCAP 5120
#define NRT (NNODES / 16)               // 3125
#define EPB 4096
#define NBE ((ETOT + EPB - 1) / EPB)    // 403
#define LOG2E 1.44269504f

typedef _Float16 v2h __attribute__((ext_vector_type(2)));
typedef _Float16 v8h __attribute__((ext_vector_type(8)));
typedef float    v4f __attribute__((ext_vector_type(4)));

__device__ __forceinline__ float hdot2v(v2h a, v2h b, float c) {
#if __has_builtin(__builtin_amdgcn_fdot2)
    return __builtin_amdgcn_fdot2(a, b, c, false);
#else
    return c + (float)a.x * (float)b.x + (float)a.y * (float)b.y;
#endif
}

__device__ __forceinline__ float fexp2(float t) {
#if __has_builtin(__builtin_amdgcn_exp2f)
    return __builtin_amdgcn_exp2f(t);
#else
    return exp2f(t);
#endif
}

// ---------------------------------------------------------------------------
// Merged prep: blocks [0,NBE) partition edges; blocks [NBE,NBE+192) pack W.
// ---------------------------------------------------------------------------
__global__ __launch_bounds__(256) void prep_kernel(
    const int* __restrict__ src, const int* __restrict__ dst,
    int* __restrict__ bcur, unsigned int* __restrict__ pairs,
    const float* __restrict__ Wl, const float* __restrict__ Wr,
    const float* __restrict__ Wlmu, const float* __restrict__ Wllv,
    const float* __restrict__ Wrmu, const float* __restrict__ Wrlv,
    __half* __restrict__ WT, __half* __restrict__ WT2)
{
    if (blockIdx.x >= NBE) {
        int id = (blockIdx.x - NBE) * 256 + threadIdx.x;
        if (id < 32768) {
            int k = id >> 8, c = id & 255;
            float v = (c < 128) ? Wl[k * 128 + c] : Wr[k * 128 + (c - 128)];
            WT[c * 128 + k] = __float2half(v);
        } else if (id < 49152) {
            int loc = id - 32768;
            int k = loc >> 7, c = loc & 127;
            int sel = c >> 5, cc = c & 31;
            const float* W = sel == 0 ? Wlmu : sel == 1 ? Wllv : sel == 2 ? Wrmu : Wrlv;
            WT2[c * 128 + k] = __float2half(W[k * 32 + cc]);
        }
        return;
    }

    __shared__ int cnt[NBUCK];
    __shared__ int gbase[NBUCK];
    const int e0 = blockIdx.x * EPB;

    for (int i = threadIdx.x; i < NBUCK; i += 256) cnt[i] = 0;
    __syncthreads();

    for (int i = threadIdx.x; i < EPB; i += 256) {
        int e = e0 + i;
        if (e >= ETOT) break;
        int d = (e < EORIG) ? dst[e] : e - EORIG;
        atomicAdd(&cnt[d >> BSH], 1);
    }
    __syncthreads();

    for (int b = threadIdx.x; b < NBUCK; b += 256) {
        int c = cnt[b];
        gbase[b] = c ? (b * BCAP + atomicAdd(&bcur[b], c)) : 0;
        cnt[b] = 0;
    }
    __syncthreads();

    for (int i = threadIdx.x; i < EPB; i += 256) {
        int e = e0 + i;
        if (e >= ETOT) break;
        int s, d;
        if (e < EORIG) { s = src[e]; d = dst[e]; }
        else           { s = d = e - EORIG; }
        int b = d >> BSH;
        int slot = atomicAdd(&cnt[b], 1);
        pairs[gbase[b] + slot] = (unsigned)s | ((unsigned)(d & 127) << 16);
    }
}

// ---------------------------------------------------------------------------
// csrfill: per-bucket local hist+scan -> begend int2 + ushort csr.
// ---------------------------------------------------------------------------
__global__ __launch_bounds__(256) void csrfill_kernel(
    const unsigned int* __restrict__ pairs, const int* __restrict__ bcur,
    int2* __restrict__ begend, unsigned short* __restrict__ csr)
{
    __shared__ int cnt[128];
    __shared__ int lofs[128];
    __shared__ int scnt[128];
    const int b = blockIdx.x, n0 = b << BSH;
    const int nn = min(128, NNODES - n0);
    const int pbase = b * BCAP;
    const int pend = pbase + bcur[b];
    const int t = threadIdx.x;

    if (t < 128) { cnt[t] = 0; scnt[t] = 0; }
    __syncthreads();
    for (int i = pbase + t; i < pend; i += 256)
        atomicAdd(&cnt[pairs[i] >> 16], 1);
    __syncthreads();

    int myc = (t < 128) ? cnt[t] : 0;
    if (t < 128) lofs[t] = myc;
    __syncthreads();
    for (int off = 1; off < 128; off <<= 1) {
        int v = (t < 128 && t >= off) ? lofs[t - off] : 0;
        __syncthreads();
        if (t < 128) lofs[t] += v;
        __syncthreads();
    }
    if (t < 128) lofs[t] = pbase + lofs[t] - myc;
    __syncthreads();

    if (t < nn) begend[n0 + t] = make_int2(lofs[t], lofs[t] + myc);

    for (int i = pbase + t; i < pend; i += 256) {
        unsigned pr = pairs[i];
        int l = pr >> 16;
        int slot = atomicAdd(&scnt[l], 1);
        csr[lofs[l] + slot] = (unsigned short)(pr & 0xFFFFu);
    }
}

// ---------------------------------------------------------------------------
// Layer-1 dual linear via MFMA (16x16x32 f16).
// ---------------------------------------------------------------------------
__global__ __launch_bounds__(256) void lin1_kernel(
    const float* __restrict__ x, const __half* __restrict__ WT,
    const float* __restrict__ bl, const float* __restrict__ br,
    __half* __restrict__ xl16, __half* __restrict__ xr16)
{
    int rt = (blockIdx.x * 256 + threadIdx.x) >> 6;
    if (rt >= NRT) return;
    int l  = threadIdx.x & 63;
    int lr = l & 15, lg = l >> 4;
    int row = rt * 16 + lr;

    v8h a[4];
    const float4* xrow = reinterpret_cast<const float4*>(x + (size_t)row * 128);
    #pragma unroll
    for (int ks = 0; ks < 4; ++ks) {
        float4 f0 = xrow[ks * 8 + lg * 2];
        float4 f1 = xrow[ks * 8 + lg * 2 + 1];
        v8h t;
        t[0]=(_Float16)f0.x; t[1]=(_Float16)f0.y; t[2]=(_Float16)f0.z; t[3]=(_Float16)f0.w;
        t[4]=(_Float16)f1.x; t[5]=(_Float16)f1.y; t[6]=(_Float16)f1.z; t[7]=(_Float16)f1.w;
        a[ks] = t;
    }

    const uint4* wt4 = reinterpret_cast<const uint4*>(WT);
    #pragma unroll 4
    for (int ct = 0; ct < 16; ++ct) {
        int c = ct * 16 + lr;
        v4f acc = {0.f, 0.f, 0.f, 0.f};
        #pragma unroll
        for (int ks = 0; ks < 4; ++ks) {
            union { uint4 u; v8h h; } B;
            B.u = wt4[(size_t)c * 16 + ks * 4 + lg];
            acc = __builtin_amdgcn_mfma_f32_16x16x32_f16(a[ks], B.h, acc, 0, 0, 0);
        }
        float bb = (c < 128) ? bl[c] : br[c - 128];
        #pragma unroll
        for (int j = 0; j < 4; ++j) {
            int orow = rt * 16 + lg * 4 + j;
            __half hv = __float2half(acc[j] + bb);
            if (c < 128) xl16[(size_t)orow * 128 + c] = hv;
            else         xr16[(size_t)orow * 128 + (c - 128)] = hv;
        }
    }
}

// ---------------------------------------------------------------------------
// Layer-2 quad linear via MFMA.
// ---------------------------------------------------------------------------
__global__ __launch_bounds__(256) void lin2_kernel(
    const __half* __restrict__ h16, const __half* __restrict__ WT2,
    const float* __restrict__ blmu, const float* __restrict__ bllv,
    const float* __restrict__ brmu, const float* __restrict__ brlv,
    __half* __restrict__ xi16, __half* __restrict__ xrI16)
{
    int rt = (blockIdx.x * 256 + threadIdx.x) >> 6;
    if (rt >= NRT) return;
    int l  = threadIdx.x & 63;
    int lr = l & 15, lg = l >> 4;
    int row = rt * 16 + lr;

    v8h a[4];
    const uint4* hrow = reinterpret_cast<const uint4*>(h16 + (size_t)row * 128);
    #pragma unroll
    for (int ks = 0; ks < 4; ++ks) {
        union { uint4 u; v8h h; } A;
        A.u = hrow[ks * 4 + lg];
        a[ks] = A.h;
    }

    const uint4* wt4 = reinterpret_cast<const uint4*>(WT2);
    #pragma unroll 4
    for (int ct = 0; ct < 8; ++ct) {
        int c = ct * 16 + lr;
        v4f acc = {0.f, 0.f, 0.f, 0.f};
        #pragma unroll
        for (int ks = 0; ks < 4; ++ks) {
            union { uint4 u; v8h h; } B;
            B.u = wt4[(size_t)c * 16 + ks * 4 + lg];
            acc = __builtin_amdgcn_mfma_f32_16x16x32_f16(a[ks], B.h, acc, 0, 0, 0);
        }
        int sel = c >> 5, cc = c & 31;
        const float* bp = sel == 0 ? blmu : sel == 1 ? bllv : sel == 2 ? brmu : brlv;
        float bb = bp[cc];
        #pragma unroll
        for (int j = 0; j < 4; ++j) {
            int orow = rt * 16 + lg * 4 + j;
            __half hv = __float2half(acc[j] + bb);
            if (c < 64) xi16 [(size_t)orow * 64 + c]      = hv;
            else        xrI16[(size_t)orow * 64 + (c-64)] = hv;
        }
    }
}

// ---------------------------------------------------------------------------
// Layer-1 gather: 8 edges/iter (2 per quarter), depth-2 pipeline,
// TAIL-SPLIT main loop (no clamps/masks in steady state), 32-bit addressing.
// csr has +32 u16 slack; over-read rows land inside ws (discarded/masked).
// ---------------------------------------------------------------------------
__global__ __launch_bounds__(256) void gat_gather1(
    const __half* __restrict__ xl16, const __half* __restrict__ xr16,
    const float* __restrict__ att, const float* __restrict__ bias,
    const int2* __restrict__ begend, const unsigned short* __restrict__ csr,
    __half* __restrict__ h16)
{
    int d = (blockIdx.x * 256 + threadIdx.x) >> 6;
    if (d >= NNODES) return;
    int lane = threadIdx.x & 63;
    int quarter = lane >> 4;
    int q = lane & 15;
    int qo = quarter * 2;

    v2h xrh[4], ath[4];
    {
        union { uint4 u; v2h v[4]; } R;
        R.u = reinterpret_cast<const uint4*>(xr16)[d * 16 + q];
        #pragma unroll
        for (int j = 0; j < 4; ++j) xrh[j] = R.v[j];
        const float4* t4 = reinterpret_cast<const float4*>(att) + q * 2;
        float4 a = t4[0], b = t4[1];
        ath[0] = (v2h){(_Float16)(a.x*LOG2E), (_Float16)(a.y*LOG2E)};
        ath[1] = (v2h){(_Float16)(a.z*LOG2E), (_Float16)(a.w*LOG2E)};
        ath[2] = (v2h){(_Float16)(b.x*LOG2E), (_Float16)(b.y*LOG2E)};
        ath[3] = (v2h){(_Float16)(b.z*LOG2E), (_Float16)(b.w*LOG2E)};
    }
    const v2h neg2 = (v2h){(_Float16)NEG, (_Float16)NEG};

    int2 be = begend[d];
    int beg = be.x, end = be.y;
    int deg = end - beg;                 // >= 1 (self-loop)
    int nF = deg >> 3;
    int rem = deg & 7;
    const uint4* xlu = reinterpret_cast<const uint4*>(xl16);

    float den = 0.f;
    float acc[8] = {0.f,0.f,0.f,0.f,0.f,0.f,0.f,0.f};

    auto computeU = [&](uint4 U) {       // unmasked (main loop)
        union { uint4 u; v2h v[4]; } X; X.u = U;
        float t = 0.f;
        #pragma unroll
        for (int j = 0; j < 4; ++j) {
            v2h s = X.v[j] + xrh[j];
            v2h l = __builtin_elementwise_max(s, s * neg2);
            t = hdot2v(l, ath[j], t);
        }
        t += __shfl_xor(t, 1, 64);
        t += __shfl_xor(t, 2, 64);
        float p = fexp2(t);
        den += p;
        #pragma unroll
        for (int j = 0; j < 4; ++j) {
            acc[2*j]   += p * (float)X.v[j].x;
            acc[2*j+1] += p * (float)X.v[j].y;
        }
    };
    auto computeM = [&](uint4 U, bool val) {   // masked (tail)
        union { uint4 u; v2h v[4]; } X; X.u = U;
        float t = 0.f;
        #pragma unroll
        for (int j = 0; j < 4; ++j) {
            v2h s = X.v[j] + xrh[j];
            v2h l = __builtin_elementwise_max(s, s * neg2);
            t = hdot2v(l, ath[j], t);
        }
        t += __shfl_xor(t, 1, 64);
        t += __shfl_xor(t, 2, 64);
        float p = val ? fexp2(t) : 0.f;
        den += p;
        #pragma unroll
        for (int j = 0; j < 4; ++j) {
            acc[2*j]   += p * (float)X.v[j].x;
            acc[2*j+1] += p * (float)X.v[j].y;
        }
    };

    // depth-2 pipeline prologue (no clamps; over-reads safe)
    int iA0 = csr[beg + qo],     iA1 = csr[beg + qo + 1];
    uint4 rA0 = xlu[iA0 * 16 + q], rA1 = xlu[iA1 * 16 + q];
    int iB0 = csr[beg + 8 + qo], iB1 = csr[beg + 8 + qo + 1];

    for (int it = 0; it < nF; ++it) {
        int b2 = beg + (it + 2) * 8;
        int iC0 = csr[b2 + qo], iC1 = csr[b2 + qo + 1];
        uint4 rB0 = xlu[iB0 * 16 + q];
        uint4 rB1 = xlu[iB1 * 16 + q];
        computeU(rA0);
        computeU(rA1);
        rA0 = rB0; rA1 = rB1;
        iB0 = iC0; iB1 = iC1;
    }
    // tail: drained rA holds rows for group nF (garbage rows masked out)
    if (rem) {
        computeM(rA0, qo < rem);
        computeM(rA1, qo + 1 < rem);
    }

    den += __shfl_xor(den, 16, 64);
    den += __shfl_xor(den, 32, 64);
    #pragma unroll
    for (int j = 0; j < 8; ++j) {
        acc[j] += __shfl_xor(acc[j], 16, 64);
        acc[j] += __shfl_xor(acc[j], 32, 64);
    }

    if (quarter == 0) {
        float r = 1.f / den;
        const float4* bp = reinterpret_cast<const float4*>(bias) + q * 2;
        float4 ba = bp[0], bb = bp[1];
        __half hv[8];
        hv[0] = __float2half(fmaxf(acc[0]*r+ba.x, 0.f));
        hv[1] = __float2half(fmaxf(acc[1]*r+ba.y, 0.f));
        hv[2] = __float2half(fmaxf(acc[2]*r+ba.z, 0.f));
        hv[3] = __float2half(fmaxf(acc[3]*r+ba.w, 0.f));
        hv[4] = __float2half(fmaxf(acc[4]*r+bb.x, 0.f));
        hv[5] = __float2half(fmaxf(acc[5]*r+bb.y, 0.f));
        hv[6] = __float2half(fmaxf(acc[6]*r+bb.z, 0.f));
        hv[7] = __float2half(fmaxf(acc[7]*r+bb.w, 0.f));
        *reinterpret_cast<uint4*>(&h16[(size_t)d * 128 + q * 8]) =
            *reinterpret_cast<uint4*>(hv);
    }
}

// ---------------------------------------------------------------------------
// Layer-2 gather: 8 edges/iter (1 per oct), depth-2 pipeline, tail-split,
// [mu|lv] interleaved 128B rows.
// ---------------------------------------------------------------------------
__global__ __launch_bounds__(256) void gat_gather2(
    const __half* __restrict__ xi16, const __half* __restrict__ xrI16,
    const float* __restrict__ atmu, const float* __restrict__ atlv,
    const float* __restrict__ bmu,  const float* __restrict__ blv,
    const int2* __restrict__ begend, const unsigned short* __restrict__ csr,
    float* __restrict__ out)
{
    int d = (blockIdx.x * 256 + threadIdx.x) >> 6;
    if (d >= NNODES) return;
    int lane = threadIdx.x & 63;
    int oct = lane >> 3;
    int r   = lane & 7;
    bool lv = r >= 4;
    int cq  = lv ? r - 4 : r;

    v2h xrh[4], ath[4];
    {
        union { uint4 u; v2h v[4]; } R;
        R.u = reinterpret_cast<const uint4*>(xrI16)[d * 8 + r];
        #pragma unroll
        for (int j = 0; j < 4; ++j) xrh[j] = R.v[j];
        const float4* t4 = reinterpret_cast<const float4*>(lv ? atlv : atmu) + cq * 2;
        float4 a = t4[0], b = t4[1];
        ath[0] = (v2h){(_Float16)(a.x*LOG2E), (_Float16)(a.y*LOG2E)};
        ath[1] = (v2h){(_Float16)(a.z*LOG2E), (_Float16)(a.w*LOG2E)};
        ath[2] = (v2h){(_Float16)(b.x*LOG2E), (_Float16)(b.y*LOG2E)};
        ath[3] = (v2h){(_Float16)(b.z*LOG2E), (_Float16)(b.w*LOG2E)};
    }
    const v2h neg2 = (v2h){(_Float16)NEG, (_Float16)NEG};

    int2 be = begend[d];
    int beg = be.x, end = be.y;
    int deg = end - beg;
    int nF = deg >> 3;
    int rem = deg & 7;
    const uint4* xiu = reinterpret_cast<const uint4*>(xi16);

    float den = 0.f;
    float acc[8] = {0.f,0.f,0.f,0.f,0.f,0.f,0.f,0.f};

    auto computeU = [&](uint4 U) {
        union { uint4 u; v2h v[4]; } X; X.u = U;
        float t = 0.f;
        #pragma unroll
        for (int j = 0; j < 4; ++j) {
            v2h s = X.v[j] + xrh[j];
            v2h l = __builtin_elementwise_max(s, s * neg2);
            t = hdot2v(l, ath[j], t);
        }
        t += __shfl_xor(t, 1, 64);
        t += __shfl_xor(t, 2, 64);
        float p = fexp2(t);
        den += p;
        #pragma unroll
        for (int j = 0; j < 4; ++j) {
            acc[2*j]   += p * (float)X.v[j].x;
            acc[2*j+1] += p * (float)X.v[j].y;
        }
    };
    auto computeM = [&](uint4 U, bool val) {
        union { uint4 u; v2h v[4]; } X; X.u = U;
        float t = 0.f;
        #pragma unroll
        for (int j = 0; j < 4; ++j) {
            v2h s = X.v[j] + xrh[j];
            v2h l = __builtin_elementwise_max(s, s * neg2);
            t = hdot2v(l, ath[j], t);
        }
        t += __shfl_xor(t, 1, 64);
        t += __shfl_xor(t, 2, 64);
        float p = val ? fexp2(t) : 0.f;
        den += p;
        #pragma unroll
        for (int j = 0; j < 4; ++j) {
            acc[2*j]   += p * (float)X.v[j].x;
            acc[2*j+1] += p * (float)X.v[j].y;
        }
    };

    int iA = csr[beg + oct];
    uint4 rA = xiu[iA * 8 + r];
    int iB = csr[beg + 8 + oct];

    for (int it = 0; it < nF; ++it) {
        int iC = csr[beg + (it + 2) * 8 + oct];
        uint4 rB = xiu[iB * 8 + r];
        computeU(rA);
        rA = rB; iB = iC;
    }
    if (rem) computeM(rA, oct < rem);

    den += __shfl_xor(den, 8, 64);
    den += __shfl_xor(den, 16, 64);
    den += __shfl_xor(den, 32, 64);
    #pragma unroll
    for (int j = 0; j < 8; ++j) {
        acc[j] += __shfl_xor(acc[j], 8, 64);
        acc[j] += __shfl_xor(acc[j], 16, 64);
        acc[j] += __shfl_xor(acc[j], 32, 64);
    }

    if (oct == 0) {
        float rr = 1.f / den;
        const float4* bp = reinterpret_cast<const float4*>(lv ? blv : bmu) + cq * 2;
        float4 ba = bp[0], bb = bp[1];
        float4 o1 = make_float4(acc[0]*rr+ba.x, acc[1]*rr+ba.y,
                                acc[2]*rr+ba.z, acc[3]*rr+ba.w);
        float4 o2 = make_float4(acc[4]*rr+bb.x, acc[5]*rr+bb.y,
                                acc[6]*rr+bb.z, acc[7]*rr+bb.w);
        float* base_out = out + (lv ? 1600000 : 0);
        float4* op = reinterpret_cast<float4*>(base_out) + (size_t)d * 8 + cq * 2;
        op[0] = o1; op[1] = o2;
    }
}

extern "C" void kernel_launch(void* const* d_in, const int* in_sizes, int n_in,
                              void* d_out, int out_size, void* d_ws, size_t ws_size,
                              hipStream_t stream) {
    const float* x    = (const float*)d_in[0];
    const int*   ei   = (const int*)d_in[1];
    const float* Wl1  = (const float*)d_in[2];
    const float* bl1  = (const float*)d_in[3];
    const float* Wr1  = (const float*)d_in[4];
    const float* br1  = (const float*)d_in[5];
    const float* att1 = (const float*)d_in[6];
    const float* b1   = (const float*)d_in[7];
    const float* Wlmu = (const float*)d_in[8];
    const float* blmu = (const float*)d_in[9];
    const float* Wrmu = (const float*)d_in[10];
    const float* brmu = (const float*)d_in[11];
    const float* atmu = (const float*)d_in[12];
    const float* bmu  = (const float*)d_in[13];
    const float* Wllv = (const float*)d_in[14];
    const float* bllv = (const float*)d_in[15];
    const float* Wrlv = (const float*)d_in[16];
    const float* brlv = (const float*)d_in[17];
    const float* atlv = (const float*)d_in[18];
    const float* blv  = (const float*)d_in[19];

    float* out = (float*)d_out;
    float* ws  = (float*)d_ws;

    __half* xl16 = (__half*)ws;                      // 6.4M halves
    __half* xr16 = (__half*)(ws + 3200000);          // 6.4M halves
    __half* h16  = (__half*)(ws + 6400000);          // 6.4M halves
    __half* WT   = (__half*)(ws + 9600000);          // 32768 halves
    __half* WT2  = (__half*)(ws + 9620000);          // 16384 halves

    __half* xi16  = (__half*)ws;                     // aliases (dead xl16)
    __half* xrI16 = (__half*)(ws + 1600000);

    int* ip = (int*)(ws + 10000000);
    unsigned int*   pairs  = (unsigned int*)ip;               // 2,001,920
    int*            bcur   = ip + 2001920;                    // 392
    int2*           begend = (int2*)(ip + 2002312);           // 50,000 int2
    unsigned short* csr    = (unsigned short*)(ip + 2102312); // 2,001,920 u16 (+32 slack)

    const int* srcp = ei;
    const int* dstp = ei + EORIG;

    // ---- CSR build + weight pack ----
    hipMemsetAsync(bcur, 0, NBUCK * sizeof(int), stream);
    prep_kernel<<<NBE + 192, 256, 0, stream>>>(
        srcp, dstp, bcur, pairs, Wl1, Wr1, Wlmu, Wllv, Wrmu, Wrlv, WT, WT2);
    csrfill_kernel<<<NBUCK, 256, 0, stream>>>(pairs, bcur, begend, csr);

    // ---- layer 1 ----
    lin1_kernel<<<(NRT + 3) / 4, 256, 0, stream>>>(x, WT, bl1, br1, xl16, xr16);

    gat_gather1<<<(NNODES * 64 + 255) / 256, 256, 0, stream>>>(
        xl16, xr16, att1, b1, begend, csr, h16);

    // ---- layer 2 ----
    lin2_kernel<<<(NRT + 3) / 4, 256, 0, stream>>>(
        h16, WT2, blmu, bllv, brmu, brlv, xi16, xrI16);

    gat_gather2<<<(NNODES * 64 + 255) / 256, 256, 0, stream>>>(
        xi16, xrI16, atmu, atlv, bmu, blv, begend, csr, out);
}

// Round 17
// 187.475 us; speedup vs baseline: 1.3837x; 1.0653x over previous
//
#include <hip/hip_runtime.h>
#include <hip/hip_fp16.h>

#define NNODES 50000
#define EORIG  1600000
#define ETOT   (EORIG + NNODES)
#define NEG 0.2f
#define BSH 7
#define NBUCK ((NNODES + 127) >> BSH)   // 391
#define BCAP 5120
#define NRT (NNODES / 16)               // 3125
#define NLB ((NRT + 3) / 4)             // 782 lin1 blocks
#define EPB 4096
#define NBE ((ETOT + EPB - 1) / EPB)    // 403
#define LOG2E 1.44269504f

typedef _Float16 v2h __attribute__((ext_vector_type(2)));
typedef _Float16 v8h __attribute__((ext_vector_type(8)));
typedef float    v4f __attribute__((ext_vector_type(4)));

__device__ __forceinline__ float hdot2v(v2h a, v2h b, float c) {
#if __has_builtin(__builtin_amdgcn_fdot2)
    return __builtin_amdgcn_fdot2(a, b, c, false);
#else
    return c + (float)a.x * (float)b.x + (float)a.y * (float)b.y;
#endif
}

__device__ __forceinline__ float fexp2(float t) {
#if __has_builtin(__builtin_amdgcn_exp2f)
    return __builtin_amdgcn_exp2f(t);
#else
    return exp2f(t);
#endif
}

// ---------------------------------------------------------------------------
// Merged prep: blocks [0,NBE) partition edges; blocks [NBE,NBE+192) pack W.
// ---------------------------------------------------------------------------
__global__ __launch_bounds__(256) void prep_kernel(
    const int* __restrict__ src, const int* __restrict__ dst,
    int* __restrict__ bcur, unsigned int* __restrict__ pairs,
    const float* __restrict__ Wl, const float* __restrict__ Wr,
    const float* __restrict__ Wlmu, const float* __restrict__ Wllv,
    const float* __restrict__ Wrmu, const float* __restrict__ Wrlv,
    __half* __restrict__ WT, __half* __restrict__ WT2)
{
    if (blockIdx.x >= NBE) {
        int id = (blockIdx.x - NBE) * 256 + threadIdx.x;
        if (id < 32768) {
            int k = id >> 8, c = id & 255;
            float v = (c < 128) ? Wl[k * 128 + c] : Wr[k * 128 + (c - 128)];
            WT[c * 128 + k] = __float2half(v);
        } else if (id < 49152) {
            int loc = id - 32768;
            int k = loc >> 7, c = loc & 127;
            int sel = c >> 5, cc = c & 31;
            const float* W = sel == 0 ? Wlmu : sel == 1 ? Wllv : sel == 2 ? Wrmu : Wrlv;
            WT2[c * 128 + k] = __float2half(W[k * 32 + cc]);
        }
        return;
    }

    __shared__ int cnt[NBUCK];
    __shared__ int gbase[NBUCK];
    const int e0 = blockIdx.x * EPB;

    for (int i = threadIdx.x; i < NBUCK; i += 256) cnt[i] = 0;
    __syncthreads();

    for (int i = threadIdx.x; i < EPB; i += 256) {
        int e = e0 + i;
        if (e >= ETOT) break;
        int d = (e < EORIG) ? dst[e] : e - EORIG;
        atomicAdd(&cnt[d >> BSH], 1);
    }
    __syncthreads();

    for (int b = threadIdx.x; b < NBUCK; b += 256) {
        int c = cnt[b];
        gbase[b] = c ? (b * BCAP + atomicAdd(&bcur[b], c)) : 0;
        cnt[b] = 0;
    }
    __syncthreads();

    for (int i = threadIdx.x; i < EPB; i += 256) {
        int e = e0 + i;
        if (e >= ETOT) break;
        int s, d;
        if (e < EORIG) { s = src[e]; d = dst[e]; }
        else           { s = d = e - EORIG; }
        int b = d >> BSH;
        int slot = atomicAdd(&cnt[b], 1);
        pairs[gbase[b] + slot] = (unsigned)s | ((unsigned)(d & 127) << 16);
    }
}

// ---------------------------------------------------------------------------
// MERGED: blocks [0,NBUCK) = csrfill; blocks [NBUCK,NBUCK+NLB) = lin1 (MFMA).
// The two halves are independent -> they overlap on different CUs.
// ---------------------------------------------------------------------------
__global__ __launch_bounds__(256) void fill_lin1_kernel(
    const unsigned int* __restrict__ pairs, const int* __restrict__ bcur,
    int2* __restrict__ begend, unsigned short* __restrict__ csr,
    const float* __restrict__ x, const __half* __restrict__ WT,
    const float* __restrict__ bl, const float* __restrict__ br,
    __half* __restrict__ xl16, __half* __restrict__ xr16)
{
    if (blockIdx.x < NBUCK) {
        // ---------------- csrfill ----------------
        __shared__ int cnt[128];
        __shared__ int lofs[128];
        __shared__ int scnt[128];
        const int b = blockIdx.x, n0 = b << BSH;
        const int nn = min(128, NNODES - n0);
        const int pbase = b * BCAP;
        const int pend = pbase + bcur[b];
        const int t = threadIdx.x;

        if (t < 128) { cnt[t] = 0; scnt[t] = 0; }
        __syncthreads();
        for (int i = pbase + t; i < pend; i += 256)
            atomicAdd(&cnt[pairs[i] >> 16], 1);
        __syncthreads();

        int myc = (t < 128) ? cnt[t] : 0;
        if (t < 128) lofs[t] = myc;
        __syncthreads();
        for (int off = 1; off < 128; off <<= 1) {
            int v = (t < 128 && t >= off) ? lofs[t - off] : 0;
            __syncthreads();
            if (t < 128) lofs[t] += v;
            __syncthreads();
        }
        if (t < 128) lofs[t] = pbase + lofs[t] - myc;
        __syncthreads();

        if (t < nn) begend[n0 + t] = make_int2(lofs[t], lofs[t] + myc);

        for (int i = pbase + t; i < pend; i += 256) {
            unsigned pr = pairs[i];
            int l = pr >> 16;
            int slot = atomicAdd(&scnt[l], 1);
            csr[lofs[l] + slot] = (unsigned short)(pr & 0xFFFFu);
        }
        return;
    }

    // ---------------- lin1 (MFMA dual linear) ----------------
    int rt = ((blockIdx.x - NBUCK) * 256 + threadIdx.x) >> 6;
    if (rt >= NRT) return;
    int l  = threadIdx.x & 63;
    int lr = l & 15, lg = l >> 4;
    int row = rt * 16 + lr;

    v8h a[4];
    const float4* xrow = reinterpret_cast<const float4*>(x + (size_t)row * 128);
    #pragma unroll
    for (int ks = 0; ks < 4; ++ks) {
        float4 f0 = xrow[ks * 8 + lg * 2];
        float4 f1 = xrow[ks * 8 + lg * 2 + 1];
        v8h t;
        t[0]=(_Float16)f0.x; t[1]=(_Float16)f0.y; t[2]=(_Float16)f0.z; t[3]=(_Float16)f0.w;
        t[4]=(_Float16)f1.x; t[5]=(_Float16)f1.y; t[6]=(_Float16)f1.z; t[7]=(_Float16)f1.w;
        a[ks] = t;
    }

    const uint4* wt4 = reinterpret_cast<const uint4*>(WT);
    #pragma unroll 4
    for (int ct = 0; ct < 16; ++ct) {
        int c = ct * 16 + lr;
        v4f acc = {0.f, 0.f, 0.f, 0.f};
        #pragma unroll
        for (int ks = 0; ks < 4; ++ks) {
            union { uint4 u; v8h h; } B;
            B.u = wt4[(size_t)c * 16 + ks * 4 + lg];
            acc = __builtin_amdgcn_mfma_f32_16x16x32_f16(a[ks], B.h, acc, 0, 0, 0);
        }
        float bb = (c < 128) ? bl[c] : br[c - 128];
        #pragma unroll
        for (int j = 0; j < 4; ++j) {
            int orow = rt * 16 + lg * 4 + j;
            __half hv = __float2half(acc[j] + bb);
            if (c < 128) xl16[(size_t)orow * 128 + c] = hv;
            else         xr16[(size_t)orow * 128 + (c - 128)] = hv;
        }
    }
}

// ---------------------------------------------------------------------------
// Layer-2 quad linear via MFMA.
// ---------------------------------------------------------------------------
__global__ __launch_bounds__(256) void lin2_kernel(
    const __half* __restrict__ h16, const __half* __restrict__ WT2,
    const float* __restrict__ blmu, const float* __restrict__ bllv,
    const float* __restrict__ brmu, const float* __restrict__ brlv,
    __half* __restrict__ xi16, __half* __restrict__ xrI16)
{
    int rt = (blockIdx.x * 256 + threadIdx.x) >> 6;
    if (rt >= NRT) return;
    int l  = threadIdx.x & 63;
    int lr = l & 15, lg = l >> 4;
    int row = rt * 16 + lr;

    v8h a[4];
    const uint4* hrow = reinterpret_cast<const uint4*>(h16 + (size_t)row * 128);
    #pragma unroll
    for (int ks = 0; ks < 4; ++ks) {
        union { uint4 u; v8h h; } A;
        A.u = hrow[ks * 4 + lg];
        a[ks] = A.h;
    }

    const uint4* wt4 = reinterpret_cast<const uint4*>(WT2);
    #pragma unroll 4
    for (int ct = 0; ct < 8; ++ct) {
        int c = ct * 16 + lr;
        v4f acc = {0.f, 0.f, 0.f, 0.f};
        #pragma unroll
        for (int ks = 0; ks < 4; ++ks) {
            union { uint4 u; v8h h; } B;
            B.u = wt4[(size_t)c * 16 + ks * 4 + lg];
            acc = __builtin_amdgcn_mfma_f32_16x16x32_f16(a[ks], B.h, acc, 0, 0, 0);
        }
        int sel = c >> 5, cc = c & 31;
        const float* bp = sel == 0 ? blmu : sel == 1 ? bllv : sel == 2 ? brmu : brlv;
        float bb = bp[cc];
        #pragma unroll
        for (int j = 0; j < 4; ++j) {
            int orow = rt * 16 + lg * 4 + j;
            __half hv = __float2half(acc[j] + bb);
            if (c < 64) xi16 [(size_t)orow * 64 + c]      = hv;
            else        xrI16[(size_t)orow * 64 + (c-64)] = hv;
        }
    }
}

// ---------------------------------------------------------------------------
// Layer-1 gather (r16 best): 8 edges/iter, depth-2 pipeline, tail-split,
// 32-bit addressing; csr over-reads land inside ws (masked in tail).
// ---------------------------------------------------------------------------
__global__ __launch_bounds__(256) void gat_gather1(
    const __half* __restrict__ xl16, const __half* __restrict__ xr16,
    const float* __restrict__ att, const float* __restrict__ bias,
    const int2* __restrict__ begend, const unsigned short* __restrict__ csr,
    __half* __restrict__ h16)
{
    int d = (blockIdx.x * 256 + threadIdx.x) >> 6;
    if (d >= NNODES) return;
    int lane = threadIdx.x & 63;
    int quarter = lane >> 4;
    int q = lane & 15;
    int qo = quarter * 2;

    v2h xrh[4], ath[4];
    {
        union { uint4 u; v2h v[4]; } R;
        R.u = reinterpret_cast<const uint4*>(xr16)[d * 16 + q];
        #pragma unroll
        for (int j = 0; j < 4; ++j) xrh[j] = R.v[j];
        const float4* t4 = reinterpret_cast<const float4*>(att) + q * 2;
        float4 a = t4[0], b = t4[1];
        ath[0] = (v2h){(_Float16)(a.x*LOG2E), (_Float16)(a.y*LOG2E)};
        ath[1] = (v2h){(_Float16)(a.z*LOG2E), (_Float16)(a.w*LOG2E)};
        ath[2] = (v2h){(_Float16)(b.x*LOG2E), (_Float16)(b.y*LOG2E)};
        ath[3] = (v2h){(_Float16)(b.z*LOG2E), (_Float16)(b.w*LOG2E)};
    }
    const v2h neg2 = (v2h){(_Float16)NEG, (_Float16)NEG};

    int2 be = begend[d];
    int beg = be.x, end = be.y;
    int deg = end - beg;
    int nF = deg >> 3;
    int rem = deg & 7;
    const uint4* xlu = reinterpret_cast<const uint4*>(xl16);

    float den = 0.f;
    float acc[8] = {0.f,0.f,0.f,0.f,0.f,0.f,0.f,0.f};

    auto computeU = [&](uint4 U) {
        union { uint4 u; v2h v[4]; } X; X.u = U;
        float t = 0.f;
        #pragma unroll
        for (int j = 0; j < 4; ++j) {
            v2h s = X.v[j] + xrh[j];
            v2h l = __builtin_elementwise_max(s, s * neg2);
            t = hdot2v(l, ath[j], t);
        }
        t += __shfl_xor(t, 1, 64);
        t += __shfl_xor(t, 2, 64);
        float p = fexp2(t);
        den += p;
        #pragma unroll
        for (int j = 0; j < 4; ++j) {
            acc[2*j]   += p * (float)X.v[j].x;
            acc[2*j+1] += p * (float)X.v[j].y;
        }
    };
    auto computeM = [&](uint4 U, bool val) {
        union { uint4 u; v2h v[4]; } X; X.u = U;
        float t = 0.f;
        #pragma unroll
        for (int j = 0; j < 4; ++j) {
            v2h s = X.v[j] + xrh[j];
            v2h l = __builtin_elementwise_max(s, s * neg2);
            t = hdot2v(l, ath[j], t);
        }
        t += __shfl_xor(t, 1, 64);
        t += __shfl_xor(t, 2, 64);
        float p = val ? fexp2(t) : 0.f;
        den += p;
        #pragma unroll
        for (int j = 0; j < 4; ++j) {
            acc[2*j]   += p * (float)X.v[j].x;
            acc[2*j+1] += p * (float)X.v[j].y;
        }
    };

    int iA0 = csr[beg + qo],     iA1 = csr[beg + qo + 1];
    uint4 rA0 = xlu[iA0 * 16 + q], rA1 = xlu[iA1 * 16 + q];
    int iB0 = csr[beg + 8 + qo], iB1 = csr[beg + 8 + qo + 1];

    for (int it = 0; it < nF; ++it) {
        int b2 = beg + (it + 2) * 8;
        int iC0 = csr[b2 + qo], iC1 = csr[b2 + qo + 1];
        uint4 rB0 = xlu[iB0 * 16 + q];
        uint4 rB1 = xlu[iB1 * 16 + q];
        computeU(rA0);
        computeU(rA1);
        rA0 = rB0; rA1 = rB1;
        iB0 = iC0; iB1 = iC1;
    }
    if (rem) {
        computeM(rA0, qo < rem);
        computeM(rA1, qo + 1 < rem);
    }

    den += __shfl_xor(den, 16, 64);
    den += __shfl_xor(den, 32, 64);
    #pragma unroll
    for (int j = 0; j < 8; ++j) {
        acc[j] += __shfl_xor(acc[j], 16, 64);
        acc[j] += __shfl_xor(acc[j], 32, 64);
    }

    if (quarter == 0) {
        float r = 1.f / den;
        const float4* bp = reinterpret_cast<const float4*>(bias) + q * 2;
        float4 ba = bp[0], bb = bp[1];
        __half hv[8];
        hv[0] = __float2half(fmaxf(acc[0]*r+ba.x, 0.f));
        hv[1] = __float2half(fmaxf(acc[1]*r+ba.y, 0.f));
        hv[2] = __float2half(fmaxf(acc[2]*r+ba.z, 0.f));
        hv[3] = __float2half(fmaxf(acc[3]*r+ba.w, 0.f));
        hv[4] = __float2half(fmaxf(acc[4]*r+bb.x, 0.f));
        hv[5] = __float2half(fmaxf(acc[5]*r+bb.y, 0.f));
        hv[6] = __float2half(fmaxf(acc[6]*r+bb.z, 0.f));
        hv[7] = __float2half(fmaxf(acc[7]*r+bb.w, 0.f));
        *reinterpret_cast<uint4*>(&h16[(size_t)d * 128 + q * 8]) =
            *reinterpret_cast<uint4*>(hv);
    }
}

// ---------------------------------------------------------------------------
// Layer-2 gather (r13 best config): 16 edges/iter (2 per oct), depth-2,
// clamped, [mu|lv] interleaved 128B rows.
// ---------------------------------------------------------------------------
__global__ __launch_bounds__(256) void gat_gather2(
    const __half* __restrict__ xi16, const __half* __restrict__ xrI16,
    const float* __restrict__ atmu, const float* __restrict__ atlv,
    const float* __restrict__ bmu,  const float* __restrict__ blv,
    const int2* __restrict__ begend, const unsigned short* __restrict__ csr,
    float* __restrict__ out)
{
    int d = (blockIdx.x * 256 + threadIdx.x) >> 6;
    if (d >= NNODES) return;
    int lane = threadIdx.x & 63;
    int oct = lane >> 3;
    int r   = lane & 7;
    bool lv = r >= 4;
    int cq  = lv ? r - 4 : r;
    int oo = oct * 2;

    v2h xrh[4], ath[4];
    {
        union { uint4 u; v2h v[4]; } R;
        R.u = reinterpret_cast<const uint4*>(xrI16)[d * 8 + r];
        #pragma unroll
        for (int j = 0; j < 4; ++j) xrh[j] = R.v[j];
        const float4* t4 = reinterpret_cast<const float4*>(lv ? atlv : atmu) + cq * 2;
        float4 a = t4[0], b = t4[1];
        ath[0] = (v2h){(_Float16)(a.x*LOG2E), (_Float16)(a.y*LOG2E)};
        ath[1] = (v2h){(_Float16)(a.z*LOG2E), (_Float16)(a.w*LOG2E)};
        ath[2] = (v2h){(_Float16)(b.x*LOG2E), (_Float16)(b.y*LOG2E)};
        ath[3] = (v2h){(_Float16)(b.z*LOG2E), (_Float16)(b.w*LOG2E)};
    }
    const v2h neg2 = (v2h){(_Float16)NEG, (_Float16)NEG};

    int2 be = begend[d];
    int beg = be.x, end = be.y;
    int nI = (end - beg + 15) >> 4;
    const uint4* xiu = reinterpret_cast<const uint4*>(xi16);

    float den = 0.f;
    float acc[8] = {0.f,0.f,0.f,0.f,0.f,0.f,0.f,0.f};

    auto compute = [&](uint4 U, bool val) {
        union { uint4 u; v2h v[4]; } X; X.u = U;
        float t = 0.f;
        #pragma unroll
        for (int j = 0; j < 4; ++j) {
            v2h s = X.v[j] + xrh[j];
            v2h l = __builtin_elementwise_max(s, s * neg2);
            t = hdot2v(l, ath[j], t);
        }
        t += __shfl_xor(t, 1, 64);
        t += __shfl_xor(t, 2, 64);
        float p = val ? fexp2(t) : 0.f;
        den += p;
        #pragma unroll
        for (int j = 0; j < 4; ++j) {
            acc[2*j]   += p * (float)X.v[j].x;
            acc[2*j+1] += p * (float)X.v[j].y;
        }
    };

    int  iA[2], iB[2];
    bool vA[2], vB[2];
    uint4 rA[2];

    #pragma unroll
    for (int k = 0; k < 2; ++k) {
        int s = beg + oo + k;
        vA[k] = s < end;
        iA[k] = csr[vA[k] ? s : end - 1];
    }
    #pragma unroll
    for (int k = 0; k < 2; ++k) rA[k] = xiu[iA[k] * 8 + r];
    #pragma unroll
    for (int k = 0; k < 2; ++k) {
        int s = beg + 16 + oo + k;
        vB[k] = s < end;
        iB[k] = csr[vB[k] ? s : end - 1];
    }

    for (int it = 0; it < nI; ++it) {
        int b2 = beg + (it + 2) * 16;
        int  iC[2]; bool vC[2];
        #pragma unroll
        for (int k = 0; k < 2; ++k) {
            int s = b2 + oo + k;
            vC[k] = s < end;
            iC[k] = csr[vC[k] ? s : end - 1];
        }
        uint4 rB[2];
        #pragma unroll
        for (int k = 0; k < 2; ++k) rB[k] = xiu[iB[k] * 8 + r];
        #pragma unroll
        for (int k = 0; k < 2; ++k) compute(rA[k], vA[k]);
        #pragma unroll
        for (int k = 0; k < 2; ++k) {
            rA[k] = rB[k]; vA[k] = vB[k];
            iB[k] = iC[k]; vB[k] = vC[k];
        }
    }

    den += __shfl_xor(den, 8, 64);
    den += __shfl_xor(den, 16, 64);
    den += __shfl_xor(den, 32, 64);
    #pragma unroll
    for (int j = 0; j < 8; ++j) {
        acc[j] += __shfl_xor(acc[j], 8, 64);
        acc[j] += __shfl_xor(acc[j], 16, 64);
        acc[j] += __shfl_xor(acc[j], 32, 64);
    }

    if (oct == 0) {
        float rr = 1.f / den;
        const float4* bp = reinterpret_cast<const float4*>(lv ? blv : bmu) + cq * 2;
        float4 ba = bp[0], bb = bp[1];
        float4 o1 = make_float4(acc[0]*rr+ba.x, acc[1]*rr+ba.y,
                                acc[2]*rr+ba.z, acc[3]*rr+ba.w);
        float4 o2 = make_float4(acc[4]*rr+bb.x, acc[5]*rr+bb.y,
                                acc[6]*rr+bb.z, acc[7]*rr+bb.w);
        float* base_out = out + (lv ? 1600000 : 0);
        float4* op = reinterpret_cast<float4*>(base_out) + (size_t)d * 8 + cq * 2;
        op[0] = o1; op[1] = o2;
    }
}

extern "C" void kernel_launch(void* const* d_in, const int* in_sizes, int n_in,
                              void* d_out, int out_size, void* d_ws, size_t ws_size,
                              hipStream_t stream) {
    const float* x    = (const float*)d_in[0];
    const int*   ei   = (const int*)d_in[1];
    const float* Wl1  = (const float*)d_in[2];
    const float* bl1  = (const float*)d_in[3];
    const float* Wr1  = (const float*)d_in[4];
    const float* br1  = (const float*)d_in[5];
    const float* att1 = (const float*)d_in[6];
    const float* b1   = (const float*)d_in[7];
    const float* Wlmu = (const float*)d_in[8];
    const float* blmu = (const float*)d_in[9];
    const float* Wrmu = (const float*)d_in[10];
    const float* brmu = (const float*)d_in[11];
    const float* atmu = (const float*)d_in[12];
    const float* bmu  = (const float*)d_in[13];
    const float* Wllv = (const float*)d_in[14];
    const float* bllv = (const float*)d_in[15];
    const float* Wrlv = (const float*)d_in[16];
    const float* brlv = (const float*)d_in[17];
    const float* atlv = (const float*)d_in[18];
    const float* blv  = (const float*)d_in[19];

    float* out = (float*)d_out;
    float* ws  = (float*)d_ws;

    __half* xl16 = (__half*)ws;                      // 6.4M halves
    __half* xr16 = (__half*)(ws + 3200000);          // 6.4M halves
    __half* h16  = (__half*)(ws + 6400000);          // 6.4M halves
    __half* WT   = (__half*)(ws + 9600000);          // 32768 halves
    __half* WT2  = (__half*)(ws + 9620000);          // 16384 halves

    __half* xi16  = (__half*)ws;                     // aliases (dead xl16)
    __half* xrI16 = (__half*)(ws + 1600000);

    int* ip = (int*)(ws + 10000000);
    unsigned int*   pairs  = (unsigned int*)ip;               // 2,001,920
    int*            bcur   = ip + 2001920;                    // 392
    int2*           begend = (int2*)(ip + 2002312);           // 50,000 int2
    unsigned short* csr    = (unsigned short*)(ip + 2102312); // 2,001,920 u16

    const int* srcp = ei;
    const int* dstp = ei + EORIG;

    // ---- CSR partition + weight pack ----
    hipMemsetAsync(bcur, 0, NBUCK * sizeof(int), stream);
    prep_kernel<<<NBE + 192, 256, 0, stream>>>(
        srcp, dstp, bcur, pairs, Wl1, Wr1, Wlmu, Wllv, Wrmu, Wrlv, WT, WT2);

    // ---- csrfill || lin1 (independent; merged launch for overlap) ----
    fill_lin1_kernel<<<NBUCK + NLB, 256, 0, stream>>>(
        pairs, bcur, begend, csr, x, WT, bl1, br1, xl16, xr16);

    // ---- layer-1 gather ----
    gat_gather1<<<(NNODES * 64 + 255) / 256, 256, 0, stream>>>(
        xl16, xr16, att1, b1, begend, csr, h16);

    // ---- layer 2 ----
    lin2_kernel<<<(NRT + 3) / 4, 256, 0, stream>>>(
        h16, WT2, blmu, bllv, brmu, brlv, xi16, xrI16);

    gat_gather2<<<(NNODES * 64 + 255) / 256, 256, 0, stream>>>(
        xi16, xrI16, atmu, atlv, bmu, blv, begend, csr, out);
}